// Round 11
// baseline (102.974 us; speedup 1.0000x reference)
//
#include <hip/hip_runtime.h>
#include <math.h>

#define N_ROWS 16384
#define D_INP  1024
#define D_LAT  128
#define KC     256
#define EPS_F  1e-8f
#define NBLK   1280

typedef _Float16 half8v __attribute__((ext_vector_type(8))); // 8 fp16
typedef __attribute__((ext_vector_type(4))) float floatx4;   // mfma C/D
typedef __attribute__((ext_vector_type(4))) float f4v;

__device__ __forceinline__ unsigned short f2h(float f) {
    _Float16 h = (_Float16)f;
    unsigned short u;
    __builtin_memcpy(&u, &h, 2);
    return u;
}
__device__ __forceinline__ float h2f(unsigned short u) {
    _Float16 h;
    __builtin_memcpy(&h, &u, 2);
    return (float)h;
}

// ---------------------------------------------------------------------------
// Prep: R -> fp16 row-major (phase A B-op) and fp16 transposed (phase B B-op),
// plus r2[k].  Block b handles centers 2b, 2b+1.  Coalesced, one-time.
// ---------------------------------------------------------------------------
__global__ __launch_bounds__(256) void prep_kernel(const float* __restrict__ R,
        unsigned short* __restrict__ Rf16, unsigned short* __restrict__ Rt16,
        float* __restrict__ r2) {
    const int t = threadIdx.x;
    const int kc = blockIdx.x * 2 + (t >> 7);
    const int d = t & 127;
    const float v = R[kc * D_LAT + d];
    Rf16[kc * D_LAT + d] = f2h(v);
    Rt16[d * KC + kc] = f2h(v);
    float sq = v * v;
    for (int off = 32; off > 0; off >>= 1) sq += __shfl_down(sq, off);
    __shared__ float s4[4];
    if ((t & 63) == 0) s4[t >> 6] = sq;
    __syncthreads();
    if (t == 0)   r2[kc] = s4[0] + s4[1];
    if (t == 128) r2[kc] = s4[2] + s4[3];
}

// ---------------------------------------------------------------------------
// Fused kernel, 1280 blocks x 512 threads (R8 structure + last-block finalize).
//   bid%5==0 : cluster block (cid = bid/5), 64 rows; B-frags of Rf16/Rt16
//              register-resident, reused across 4 row-tiles.
//   else     : recon block (rid), register-batched nt float4 stream.
// Last-arriving block (atomic counter) reduces partials in FIXED order.
// ---------------------------------------------------------------------------
__global__ __launch_bounds__(512) void fused_kernel(
        const float* __restrict__ x, const float* __restrict__ a,
        const float* __restrict__ h,
        const unsigned short* __restrict__ Rf16,
        const unsigned short* __restrict__ Rt16,
        const float* __restrict__ r2w,
        float* __restrict__ pr, float* __restrict__ pc,
        unsigned* __restrict__ counter, float* __restrict__ out) {
    __shared__ unsigned short sh16[64 * 136];  // h fp16, row stride 136 (17.4 KB)
    __shared__ unsigned short eL[64 * 264];    // e fp16, row stride 264 (33.8 KB)
    __shared__ float sumsL[64][16];            // 4 KB
    __shared__ float h2L[64];
    __shared__ float invL[64];
    __shared__ float swL[8];
    __shared__ int lastFlag;

    const int bid = blockIdx.x;
    const int tid = threadIdx.x;
    const int wv = tid >> 6, lane = tid & 63;

    if (bid % 5 != 0) {
        // ---------------- recon ----------------
        const int rid = bid - 1 - bid / 5;               // 0..1023
        const int gid = rid * 512 + tid;                 // 524,288 threads
        const f4v* x4 = (const f4v*)x;
        const f4v* a4 = (const f4v*)a;
        f4v xv[8], av[8];
#pragma unroll
        for (int it = 0; it < 8; ++it) {
            const int i = gid + it * (512 * 1024);
            xv[it] = __builtin_nontemporal_load(x4 + i);
            av[it] = __builtin_nontemporal_load(a4 + i);
        }
        float a0 = 0.f, a1 = 0.f, a2 = 0.f, a3 = 0.f;
#pragma unroll
        for (int it = 0; it < 8; ++it) {
            const float d0 = xv[it].x - av[it].x, d1 = xv[it].y - av[it].y;
            const float d2 = xv[it].z - av[it].z, d3 = xv[it].w - av[it].w;
            a0 = fmaf(d0, d0, a0);
            a1 = fmaf(d1, d1, a1);
            a2 = fmaf(d2, d2, a2);
            a3 = fmaf(d3, d3, a3);
        }
        float acc = (a0 + a1) + (a2 + a3);
        for (int off = 32; off > 0; off >>= 1) acc += __shfl_down(acc, off);
        if (lane == 0) swL[wv] = acc;
        __syncthreads();
        if (tid == 0) {
            float t = 0.f;
#pragma unroll
            for (int w = 0; w < 8; ++w) t += swL[w];
            pr[rid] = t;
        }
    } else {
        // ---------------- cluster ----------------
        const int cid = bid / 5;                 // 0..255
        const int rbase = cid * 64;
        const int g = lane >> 4, c = lane & 15;

        // stage h (64 rows x 128): fp16 convert; per-row |h|^2.
        {
            const int r = tid >> 3, c8 = tid & 7;
            const float* hrow = h + (size_t)(rbase + r) * D_LAT;
            float s = 0.f;
#pragma unroll
            for (int q = 0; q < 4; ++q) {
                const int c4 = c8 + q * 8;
                const f4v v = __builtin_nontemporal_load((const f4v*)(hrow + c4 * 4));
                sh16[r * 136 + c4 * 4 + 0] = f2h(v.x);
                sh16[r * 136 + c4 * 4 + 1] = f2h(v.y);
                sh16[r * 136 + c4 * 4 + 2] = f2h(v.z);
                sh16[r * 136 + c4 * 4 + 3] = f2h(v.w);
                s = fmaf(v.x, v.x, s);
                s = fmaf(v.y, v.y, s);
                s = fmaf(v.z, v.z, s);
                s = fmaf(v.w, v.w, s);
            }
            s += __shfl_xor(s, 1);
            s += __shfl_xor(s, 2);
            s += __shfl_xor(s, 4);
            if ((tid & 7) == 0) h2L[r] = s;
        }
        __syncthreads();

        // ---- phase A: S = h.R^T (fp16 mfma); B-frags in regs, reused 4x ----
        {
            half8v bA[2][4];
#pragma unroll
            for (int tt = 0; tt < 2; ++tt) {
                const int kc = (wv * 2 + tt) * 16 + c;
#pragma unroll
                for (int ks = 0; ks < 4; ++ks)
                    bA[tt][ks] = *(const half8v*)(Rf16 + (size_t)kc * D_LAT + ks * 32 + g * 8);
            }
            const float r2v[2] = {r2w[wv * 32 + c], r2w[wv * 32 + 16 + c]};
#pragma unroll
            for (int rt = 0; rt < 4; ++rt) {
                half8v aH[4];
#pragma unroll
                for (int ks = 0; ks < 4; ++ks)
                    aH[ks] = *(const half8v*)&sh16[(rt * 16 + c) * 136 + ks * 32 + g * 8];
                float h2a[4];
#pragma unroll
                for (int i = 0; i < 4; ++i) h2a[i] = h2L[rt * 16 + 4 * g + i];
#pragma unroll
                for (int tt = 0; tt < 2; ++tt) {
                    floatx4 acc = {0.f, 0.f, 0.f, 0.f};
#pragma unroll
                    for (int ks = 0; ks < 4; ++ks)
                        acc = __builtin_amdgcn_mfma_f32_16x16x32_f16(aH[ks], bA[tt][ks], acc, 0, 0, 0);
                    const int kc = (wv * 2 + tt) * 16 + c;
#pragma unroll
                    for (int i = 0; i < 4; ++i) {
                        const float d2 = h2a[i] + r2v[tt] - 2.0f * acc[i];
                        const float e = __expf(-sqrtf(fmaxf(d2, 0.f)));
                        eL[(rt * 16 + 4 * g + i) * 264 + kc] = f2h(e);
                        float v = e;
                        v += __shfl_xor(v, 1);
                        v += __shfl_xor(v, 2);
                        v += __shfl_xor(v, 4);
                        v += __shfl_xor(v, 8);
                        if (c == 0) sumsL[rt * 16 + 4 * g + i][wv * 2 + tt] = v;
                    }
                }
            }
        }
        __syncthreads();
        if (tid < 64) {
            float t = 0.f;
#pragma unroll
            for (int j = 0; j < 16; ++j) t += sumsL[tid][j];
            invL[tid] = 1.0f / (t + EPS_F);
        }
        __syncthreads();

        // ---- phase B: wc = E.R (fp16 mfma); B-frags in regs, reused 4x ----
        {
            const int dcol = wv * 16 + c;        // 8 d-tiles over 8 waves
            half8v bB[8];
#pragma unroll
            for (int ks = 0; ks < 8; ++ks)
                bB[ks] = *(const half8v*)(Rt16 + (size_t)dcol * KC + ks * 32 + g * 8);
            float lp = 0.f;
#pragma unroll
            for (int rt = 0; rt < 4; ++rt) {
                floatx4 acc = {0.f, 0.f, 0.f, 0.f};
#pragma unroll
                for (int ks = 0; ks < 8; ++ks) {
                    const half8v ae = *(const half8v*)&eL[(rt * 16 + c) * 264 + ks * 32 + g * 8];
                    acc = __builtin_amdgcn_mfma_f32_16x16x32_f16(ae, bB[ks], acc, 0, 0, 0);
                }
#pragma unroll
                for (int i = 0; i < 4; ++i) {
                    const int row = rt * 16 + 4 * g + i;
                    const float wc = acc[i] * invL[row];
                    const float hv = h2f(sh16[row * 136 + dcol]);
                    const float df = hv - wc;
                    lp = fmaf(df, df, lp);
                }
            }
            for (int off = 32; off > 0; off >>= 1) lp += __shfl_down(lp, off);
            if (lane == 0) swL[wv] = lp;
        }
        __syncthreads();
        if (tid == 0) {
            float t = 0.f;
#pragma unroll
            for (int w = 0; w < 8; ++w) t += swL[w];
            pc[cid] = t;
        }
    }

    // ---------------- last-block finalize (deterministic fixed-order) -------
    if (tid == 0) {
        __threadfence();
        lastFlag = (atomicAdd(counter, 1u) == NBLK - 1);
    }
    __syncthreads();
    if (lastFlag) {
        __threadfence();
        float aa = 0.f, bb = 0.f;
        for (int i = tid; i < 1024; i += 512) aa += pr[i];   // fixed 2-term order
        if (tid < 256) bb = pc[tid];
        float v = aa * (1.0f / ((float)N_ROWS * (float)D_INP)) +
                  bb * (1.0f / ((float)N_ROWS * (float)D_LAT));
        for (int off = 32; off > 0; off >>= 1) v += __shfl_down(v, off);
        __syncthreads();
        if (lane == 0) swL[wv] = v;
        __syncthreads();
        if (tid == 0) {
            float t = 0.f;
#pragma unroll
            for (int w = 0; w < 8; ++w) t += swL[w];
            out[0] = t;
        }
    }
}

extern "C" void kernel_launch(void* const* d_in, const int* in_sizes, int n_in,
                              void* d_out, int out_size, void* d_ws, size_t ws_size,
                              hipStream_t stream) {
    const float* x = (const float*)d_in[0];
    const float* h = (const float*)d_in[1];
    const float* a = (const float*)d_in[2];
    const float* R = (const float*)d_in[3];
    float* out = (float*)d_out;
    char* wsb = (char*)d_ws;
    float* pr = (float*)(wsb + 0);                       // 1024 f
    float* pc = (float*)(wsb + 4096);                    // 256 f
    unsigned* counter = (unsigned*)(wsb + 8192);
    float* r2 = (float*)(wsb + 12288);                   // 256 f
    unsigned short* Rf16 = (unsigned short*)(wsb + 16384);          // 64 KiB
    unsigned short* Rt16 = (unsigned short*)(wsb + 16384 + 65536);  // 64 KiB

    hipMemsetAsync(counter, 0, 4, stream);
    prep_kernel<<<128, 256, 0, stream>>>(R, Rf16, Rt16, r2);
    fused_kernel<<<NBLK, 512, 0, stream>>>(x, a, h, Rf16, Rt16, r2, pr, pc, counter, out);
}

// Round 12
// 44.446 us; speedup vs baseline: 2.3168x; 2.3168x over previous
//
#include <hip/hip_runtime.h>
#include <math.h>

#define N_ROWS 16384
#define D_INP  1024
#define D_LAT  128
#define KC     256
#define EPS_F  1e-8f

typedef _Float16 half8v __attribute__((ext_vector_type(8))); // 8 fp16
typedef __attribute__((ext_vector_type(4))) float floatx4;   // mfma C/D
typedef __attribute__((ext_vector_type(4))) float f4v;

__device__ __forceinline__ unsigned short f2h(float f) {
    _Float16 h = (_Float16)f;
    unsigned short u;
    __builtin_memcpy(&u, &h, 2);
    return u;
}
__device__ __forceinline__ float h2f(unsigned short u) {
    _Float16 h;
    __builtin_memcpy(&h, &u, 2);
    return (float)h;
}

// ---------------------------------------------------------------------------
// Prep: R -> fp16 row-major (phase A B-op) and fp16 transposed (phase B B-op),
// plus r2[k].  Block b handles centers 2b, 2b+1.  Coalesced, one-time.
// ---------------------------------------------------------------------------
__global__ __launch_bounds__(256) void prep_kernel(const float* __restrict__ R,
        unsigned short* __restrict__ Rf16, unsigned short* __restrict__ Rt16,
        float* __restrict__ r2) {
    const int t = threadIdx.x;
    const int kc = blockIdx.x * 2 + (t >> 7);
    const int d = t & 127;
    const float v = R[kc * D_LAT + d];
    Rf16[kc * D_LAT + d] = f2h(v);
    Rt16[d * KC + kc] = f2h(v);
    float sq = v * v;
    for (int off = 32; off > 0; off >>= 1) sq += __shfl_down(sq, off);
    __shared__ float s4[4];
    if ((t & 63) == 0) s4[t >> 6] = sq;
    __syncthreads();
    if (t == 0)   r2[kc] = s4[0] + s4[1];
    if (t == 128) r2[kc] = s4[2] + s4[3];
}

// ---------------------------------------------------------------------------
// Fused kernel, 1280 blocks x 512 threads.
//   bid%5==0 : cluster block (cid = bid/5), 64 rows. B-fragments of Rf16/Rt16
//              register-resident, reused across 4 row-tiles (tables read from
//              L2 exactly once per block: ~32 MB total vs 139 MB at 16 rows).
//   else     : recon block (rid), register-batched nt float4 stream.
// NO device-scope fences / single-kernel finalize: on 8-XCD gfx950 a
// __threadfence per block costs ~60us across the grid (R10/R11 regression).
// ---------------------------------------------------------------------------
__global__ __launch_bounds__(512) void fused_kernel(
        const float* __restrict__ x, const float* __restrict__ a,
        const float* __restrict__ h,
        const unsigned short* __restrict__ Rf16,
        const unsigned short* __restrict__ Rt16,
        const float* __restrict__ r2w,
        float* __restrict__ pr, float* __restrict__ pc) {
    __shared__ unsigned short sh16[64 * 136];  // h fp16, row stride 136 (17.4 KB)
    __shared__ unsigned short eL[64 * 264];    // e fp16, row stride 264 (33.8 KB)
    __shared__ float sumsL[64][16];            // 4 KB
    __shared__ float h2L[64];
    __shared__ float invL[64];
    __shared__ float swL[8];

    const int bid = blockIdx.x;
    const int tid = threadIdx.x;
    const int wv = tid >> 6, lane = tid & 63;

    if (bid % 5 != 0) {
        // ---------------- recon ----------------
        const int rid = bid - 1 - bid / 5;               // 0..1023
        const int gid = rid * 512 + tid;                 // 524,288 threads
        const f4v* x4 = (const f4v*)x;
        const f4v* a4 = (const f4v*)a;
        f4v xv[8], av[8];
#pragma unroll
        for (int it = 0; it < 8; ++it) {
            const int i = gid + it * (512 * 1024);
            xv[it] = __builtin_nontemporal_load(x4 + i);
            av[it] = __builtin_nontemporal_load(a4 + i);
        }
        float a0 = 0.f, a1 = 0.f, a2 = 0.f, a3 = 0.f;
#pragma unroll
        for (int it = 0; it < 8; ++it) {
            const float d0 = xv[it].x - av[it].x, d1 = xv[it].y - av[it].y;
            const float d2 = xv[it].z - av[it].z, d3 = xv[it].w - av[it].w;
            a0 = fmaf(d0, d0, a0);
            a1 = fmaf(d1, d1, a1);
            a2 = fmaf(d2, d2, a2);
            a3 = fmaf(d3, d3, a3);
        }
        float acc = (a0 + a1) + (a2 + a3);
        for (int off = 32; off > 0; off >>= 1) acc += __shfl_down(acc, off);
        if (lane == 0) swL[wv] = acc;
        __syncthreads();
        if (tid == 0) {
            float t = 0.f;
#pragma unroll
            for (int w = 0; w < 8; ++w) t += swL[w];
            pr[rid] = t;
        }
        return;
    }

    // ---------------- cluster ----------------
    const int cid = bid / 5;                 // 0..255
    const int rbase = cid * 64;
    const int g = lane >> 4, c = lane & 15;

    // stage h (64 rows x 128): fp16 convert; per-row |h|^2.
    {
        const int r = tid >> 3, c8 = tid & 7;
        const float* hrow = h + (size_t)(rbase + r) * D_LAT;
        float s = 0.f;
#pragma unroll
        for (int q = 0; q < 4; ++q) {
            const int c4 = c8 + q * 8;
            const f4v v = __builtin_nontemporal_load((const f4v*)(hrow + c4 * 4));
            sh16[r * 136 + c4 * 4 + 0] = f2h(v.x);
            sh16[r * 136 + c4 * 4 + 1] = f2h(v.y);
            sh16[r * 136 + c4 * 4 + 2] = f2h(v.z);
            sh16[r * 136 + c4 * 4 + 3] = f2h(v.w);
            s = fmaf(v.x, v.x, s);
            s = fmaf(v.y, v.y, s);
            s = fmaf(v.z, v.z, s);
            s = fmaf(v.w, v.w, s);
        }
        s += __shfl_xor(s, 1);
        s += __shfl_xor(s, 2);
        s += __shfl_xor(s, 4);
        if ((tid & 7) == 0) h2L[r] = s;
    }
    __syncthreads();

    // ---- phase A: S = h.R^T (fp16 mfma). B-frags in regs, reused 4x. ----
    {
        half8v bA[2][4];
#pragma unroll
        for (int tt = 0; tt < 2; ++tt) {
            const int kc = (wv * 2 + tt) * 16 + c;
#pragma unroll
            for (int ks = 0; ks < 4; ++ks)
                bA[tt][ks] = *(const half8v*)(Rf16 + (size_t)kc * D_LAT + ks * 32 + g * 8);
        }
        const float r2v[2] = {r2w[wv * 32 + c], r2w[wv * 32 + 16 + c]};
#pragma unroll
        for (int rt = 0; rt < 4; ++rt) {
            half8v aH[4];
#pragma unroll
            for (int ks = 0; ks < 4; ++ks)
                aH[ks] = *(const half8v*)&sh16[(rt * 16 + c) * 136 + ks * 32 + g * 8];
            float h2a[4];
#pragma unroll
            for (int i = 0; i < 4; ++i) h2a[i] = h2L[rt * 16 + 4 * g + i];
#pragma unroll
            for (int tt = 0; tt < 2; ++tt) {
                floatx4 acc = {0.f, 0.f, 0.f, 0.f};
#pragma unroll
                for (int ks = 0; ks < 4; ++ks)
                    acc = __builtin_amdgcn_mfma_f32_16x16x32_f16(aH[ks], bA[tt][ks], acc, 0, 0, 0);
                const int kc = (wv * 2 + tt) * 16 + c;
#pragma unroll
                for (int i = 0; i < 4; ++i) {
                    const float d2 = h2a[i] + r2v[tt] - 2.0f * acc[i];
                    const float e = __expf(-sqrtf(fmaxf(d2, 0.f)));
                    eL[(rt * 16 + 4 * g + i) * 264 + kc] = f2h(e);
                    float v = e;
                    v += __shfl_xor(v, 1);
                    v += __shfl_xor(v, 2);
                    v += __shfl_xor(v, 4);
                    v += __shfl_xor(v, 8);
                    if (c == 0) sumsL[rt * 16 + 4 * g + i][wv * 2 + tt] = v;
                }
            }
        }
    }
    __syncthreads();
    if (tid < 64) {
        float t = 0.f;
#pragma unroll
        for (int j = 0; j < 16; ++j) t += sumsL[tid][j];
        invL[tid] = 1.0f / (t + EPS_F);
    }
    __syncthreads();

    // ---- phase B: wc = E.R (fp16 mfma). B-frags in regs, reused 4x. ----
    {
        const int dcol = wv * 16 + c;        // 8 d-tiles over 8 waves
        half8v bB[8];
#pragma unroll
        for (int ks = 0; ks < 8; ++ks)
            bB[ks] = *(const half8v*)(Rt16 + (size_t)dcol * KC + ks * 32 + g * 8);
        float lp = 0.f;
#pragma unroll
        for (int rt = 0; rt < 4; ++rt) {
            floatx4 acc = {0.f, 0.f, 0.f, 0.f};
#pragma unroll
            for (int ks = 0; ks < 8; ++ks) {
                const half8v ae = *(const half8v*)&eL[(rt * 16 + c) * 264 + ks * 32 + g * 8];
                acc = __builtin_amdgcn_mfma_f32_16x16x32_f16(ae, bB[ks], acc, 0, 0, 0);
            }
#pragma unroll
            for (int i = 0; i < 4; ++i) {
                const int row = rt * 16 + 4 * g + i;
                const float wc = acc[i] * invL[row];
                const float hv = h2f(sh16[row * 136 + dcol]);
                const float df = hv - wc;
                lp = fmaf(df, df, lp);
            }
        }
        for (int off = 32; off > 0; off >>= 1) lp += __shfl_down(lp, off);
        if (lane == 0) swL[wv] = lp;
    }
    __syncthreads();
    if (tid == 0) {
        float t = 0.f;
#pragma unroll
        for (int w = 0; w < 8; ++w) t += swL[w];
        pc[cid] = t;
    }
}

// ---------------------------------------------------------------------------
// Final reduction + means.
// ---------------------------------------------------------------------------
__global__ __launch_bounds__(256) void finalize_kernel(const float* __restrict__ pr,
                                                       const float* __restrict__ pc,
                                                       float* __restrict__ out) {
    const int tid = threadIdx.x;
    float a = 0.f, b = 0.f;
    for (int i = tid; i < 1024; i += 256) a += pr[i];
    if (tid < 256) b = pc[tid];
    float v = a * (1.0f / ((float)N_ROWS * (float)D_INP)) +
              b * (1.0f / ((float)N_ROWS * (float)D_LAT));
    for (int off = 32; off > 0; off >>= 1) v += __shfl_down(v, off);
    __shared__ float sw[4];
    if ((tid & 63) == 0) sw[tid >> 6] = v;
    __syncthreads();
    if (tid == 0) out[0] = sw[0] + sw[1] + sw[2] + sw[3];
}

extern "C" void kernel_launch(void* const* d_in, const int* in_sizes, int n_in,
                              void* d_out, int out_size, void* d_ws, size_t ws_size,
                              hipStream_t stream) {
    const float* x = (const float*)d_in[0];
    const float* h = (const float*)d_in[1];
    const float* a = (const float*)d_in[2];
    const float* R = (const float*)d_in[3];
    float* out = (float*)d_out;
    char* wsb = (char*)d_ws;
    float* pr = (float*)(wsb + 0);                       // 1024 f
    float* pc = (float*)(wsb + 8192);                    // 256 f
    float* r2 = (float*)(wsb + 12288);                   // 256 f
    unsigned short* Rf16 = (unsigned short*)(wsb + 16384);          // 64 KiB
    unsigned short* Rt16 = (unsigned short*)(wsb + 16384 + 65536);  // 64 KiB

    prep_kernel<<<128, 256, 0, stream>>>(R, Rf16, Rt16, r2);
    fused_kernel<<<1280, 512, 0, stream>>>(x, a, h, Rf16, Rt16, r2, pr, pc);
    finalize_kernel<<<1, 256, 0, stream>>>(pr, pc, out);
}